// Round 8
// baseline (199.753 us; speedup 1.0000x reference)
//
#include <hip/hip_runtime.h>
#include <hip/hip_bf16.h>
#include <hip/hip_cooperative_groups.h>
#include <math.h>

namespace cg = cooperative_groups;

#define D 128
#define INV_TAU 5.0f

typedef short bf16x8 __attribute__((ext_vector_type(8)));
typedef unsigned short u16x8 __attribute__((ext_vector_type(8)));
typedef float f32x4 __attribute__((ext_vector_type(4)));

__device__ __forceinline__ unsigned short bf16_bits(float v) {
    __hip_bfloat16 hb = __float2bfloat16(v);
    return *(unsigned short*)&hb;
}

// ============================================================================
// Coop kernel A: scatter pos -> grid.sync -> prep (partner + normalize).
// 256 blocks x 512 thr, light registers/LDS => always co-resident.
// ============================================================================
__global__ __launch_bounds__(512) void prep_all_kernel(
    const float* __restrict__ emb, const int* __restrict__ pp, int* __restrict__ pos,
    unsigned short* __restrict__ hnn, float* __restrict__ hpn,
    float* __restrict__ out, int N, int K) {
    cg::grid_group grid = cg::this_grid();
    int tid = threadIdx.x;

    for (int k = blockIdx.x * 512 + tid; k < K; k += gridDim.x * 512)
        pos[pp[2 * k]] = pp[2 * k + 1];
    if (blockIdx.x == 0 && tid == 0) *out = 0.0f;
    grid.sync();

    __shared__ int sP[4];
    __shared__ float redf[8];
    int g = tid >> 7, dd = tid & 127;  // 4 groups of 128 thr (2 waves each)
    int wv = tid >> 6, lane = tid & 63;
    int rowsPer = gridDim.x * 4;
    int total = N + K;
    int iters = (total + rowsPer - 1) / rowsPer;
    for (int it = 0; it < iters; ++it) {
        int r = it * rowsPer + blockIdx.x * 4 + g;
        bool act = r < total;
        bool isHn = act && (r < N);
        if (isHn && dd == 0) {
            int rr = r, posr = pos[rr];
            int jmax = -1;
            for (int j = N - 1; j >= 0; --j)
                if (j != rr && j != posr) { jmax = j; break; }
            int imax = -1;
            for (int i = N - 1; i >= 0; --i)
                if (i != rr && pos[i] != rr) { imax = i; break; }
            long long rowm = (jmax >= 0) ? (long long)rr * N + jmax : -1;
            long long colm = (imax >= 0) ? (long long)imax * N + rr : -1;
            sP[g] = (colm > rowm) ? (imax < 0 ? 0 : imax) : (jmax < 0 ? 0 : jmax);
        }
        __syncthreads();
        float h = 0.0f;
        int outrow = 0;
        if (act) {
            if (isHn) {
                int p = sP[g];
                h = 0.5f * (emb[(size_t)r * D + dd] + emb[(size_t)p * D + dd]);
                outrow = r;
            } else {
                int kk = r - N;
                int a = pp[2 * kk], bb = pp[2 * kk + 1];
                h = 1.5f * emb[(size_t)a * D + dd] - 0.5f * emb[(size_t)bb * D + dd];
                outrow = a;
            }
        }
        float ss = h * h;
#pragma unroll
        for (int off = 32; off > 0; off >>= 1) ss += __shfl_down(ss, off);
        if (lane == 0) redf[wv] = ss;
        __syncthreads();
        if (act) {
            float inv = 1.0f / fmaxf(sqrtf(redf[g * 2] + redf[g * 2 + 1]), 1e-8f);
            if (isHn)
                hnn[(size_t)outrow * D + dd] = bf16_bits(h * inv);
            else
                hpn[(size_t)outrow * D + dd] = h * inv;
        }
        __syncthreads();
    }
}

// ============================================================================
// K2: symmetric 128x128-tile bf16 MFMA GEMM -> sortable-u16 sims.
// Only upper-triangular tiles (trow <= tcol); off-diag tiles write both the
// tile and its transpose (independent masking). 528 blocks for N=4096.
// ============================================================================
__global__ __launch_bounds__(256) void gemm_sim_sym(const unsigned short* __restrict__ hnn,
                                                    const int* __restrict__ pos,
                                                    unsigned short* __restrict__ sims, int N) {
    __shared__ unsigned short As[128 * 136];
    __shared__ unsigned short Bs[128 * 136];
    __shared__ int pos_r[128], pos_c[128];
    int tid = threadIdx.x;
    int nT = N >> 7;
    int t = blockIdx.x, trow = 0;
    while (t >= nT - trow) { t -= nT - trow; ++trow; }
    int tcol = trow + t;
    int rowBase = trow * 128, colBase = tcol * 128;
    bool diag = (trow == tcol);
    if (tid < 128) pos_r[tid] = pos[rowBase + tid];
    else pos_c[tid - 128] = pos[colBase + tid - 128];

    u16x8 ra[8], rb[8];
#pragma unroll
    for (int i = 0; i < 8; ++i) {
        int idx = i * 256 + tid;
        int row = idx >> 4, seg = idx & 15;
        ra[i] = *(const u16x8*)&hnn[(size_t)(rowBase + row) * D + seg * 8];
        rb[i] = *(const u16x8*)&hnn[(size_t)(colBase + row) * D + seg * 8];
    }
#pragma unroll
    for (int i = 0; i < 8; ++i) {
        int idx = i * 256 + tid;
        int row = idx >> 4, seg = idx & 15;
        *(u16x8*)&As[row * 136 + seg * 8] = ra[i];
        *(u16x8*)&Bs[row * 136 + seg * 8] = rb[i];
    }
    __syncthreads();

    int wave = tid >> 6, lane = tid & 63;
    int quad = lane >> 4, l15 = lane & 15;
    int rowhalf = wave >> 1, colhalf = wave & 1;

    f32x4 acc[4][4] = {};
#pragma unroll
    for (int kk = 0; kk < 4; ++kk) {
        bf16x8 af[4], bf[4];
#pragma unroll
        for (int rt = 0; rt < 4; ++rt)
            af[rt] = *(const bf16x8*)&As[(rowhalf * 64 + rt * 16 + l15) * 136 + kk * 32 + quad * 8];
#pragma unroll
        for (int ct = 0; ct < 4; ++ct)
            bf[ct] = *(const bf16x8*)&Bs[(colhalf * 64 + ct * 16 + l15) * 136 + kk * 32 + quad * 8];
#pragma unroll
        for (int rt = 0; rt < 4; ++rt)
#pragma unroll
            for (int ct = 0; ct < 4; ++ct)
                acc[rt][ct] = __builtin_amdgcn_mfma_f32_16x16x32_bf16(af[rt], bf[ct],
                                                                     acc[rt][ct], 0, 0, 0);
    }
    __syncthreads();  // reuse As = C-tile, Bs = C^T-tile

#pragma unroll
    for (int rt = 0; rt < 4; ++rt) {
#pragma unroll
        for (int rg = 0; rg < 4; ++rg) {
            int rloc = rowhalf * 64 + rt * 16 + quad * 4 + rg;
            int r = rowBase + rloc;
            int pr = pos_r[rloc];
#pragma unroll
            for (int ct = 0; ct < 4; ++ct) {
                int cloc = colhalf * 64 + ct * 16 + l15;
                int c = colBase + cloc;
                unsigned short u = bf16_bits(acc[rt][ct][rg]);
                unsigned short sv = (u & 0x8000u) ? (unsigned short)~u
                                                  : (unsigned short)(u | 0x8000u);
                unsigned short svC = (c == r || c == pr) ? (unsigned short)0x0080 : sv;
                As[rloc * 136 + cloc] = svC;
                if (!diag) {
                    // transposed entry (c, r): masked iff r == pos[c] (r != c off-diag)
                    unsigned short svT = (r == pos_c[cloc]) ? (unsigned short)0x0080 : sv;
                    Bs[cloc * 136 + rloc] = svT;
                }
            }
        }
    }
    __syncthreads();

#pragma unroll
    for (int i = 0; i < 8; ++i) {
        int idx = i * 256 + tid;
        int row = idx >> 4, seg = idx & 15;
        *(u16x8*)&sims[(size_t)(rowBase + row) * N + colBase + seg * 8] =
            *(const u16x8*)&As[row * 136 + seg * 8];
    }
    if (!diag) {
#pragma unroll
        for (int i = 0; i < 8; ++i) {
            int idx = i * 256 + tid;
            int row = idx >> 4, seg = idx & 15;
            *(u16x8*)&sims[(size_t)(colBase + row) * N + rowBase + seg * 8] =
                *(const u16x8*)&Bs[row * 136 + seg * 8];
        }
    }
}

// ============================================================================
// Coop kernel B: wave-per-row exact rank-select + exp-sum -> grid.sync -> loss.
// 256 blocks x 512 thr (always co-resident), grid-stride over rows/pairs.
// ============================================================================
__global__ __launch_bounds__(512) void select_loss_kernel(
    const unsigned short* __restrict__ sims, const int* __restrict__ stage,
    const float* __restrict__ hpn, const int* __restrict__ pp,
    float* __restrict__ s_out, float* __restrict__ out, int N, int K, int q) {
    cg::grid_group grid = cg::this_grid();
    int wave = threadIdx.x >> 6, lane = threadIdx.x & 63;
    int wid = blockIdx.x * 8 + wave;
    int totalWaves = gridDim.x * 8;
    int st = stage[0];

    for (int row = wid; row < N; row += totalWaves) {
        const unsigned short* rp = sims + (size_t)row * N;
        unsigned s[64];
#pragma unroll
        for (int j = 0; j < 8; ++j) {
            u16x8 tv = *(const u16x8*)&rp[j * 512 + lane * 8];
#pragma unroll
            for (int e = 0; e < 8; ++e) s[j * 8 + e] = (unsigned)(unsigned short)tv[e];
        }
        unsigned T = 0;
        if (st) {
#pragma unroll
            for (int b = 15; b >= 0; --b) {
                unsigned cand = T | (1u << b);
                int cnt = 0;
#pragma unroll
                for (int i = 0; i < 64; ++i) cnt += (s[i] < cand);
#pragma unroll
                for (int off = 1; off < 64; off <<= 1) cnt += __shfl_xor(cnt, off);
                if (cnt <= q) T = cand;  // rank-q element is >= cand
            }
        }
        float sum = 0.0f;
#pragma unroll
        for (int i = 0; i < 64; ++i) {
            if (s[i] >= T) {
                unsigned raw = (s[i] & 0x8000u) ? (s[i] ^ 0x8000u) : (~s[i] & 0xFFFFu);
                sum += __expf(__uint_as_float(raw << 16) * INV_TAU);
            }
        }
#pragma unroll
        for (int off = 1; off < 64; off <<= 1) sum += __shfl_xor(sum, off);
        if (lane == 0) s_out[row] = sum;
    }
    grid.sync();

    float part = 0.0f;
    for (int k = wid; k < K; k += totalWaves) {
        int a = pp[2 * k], b = pp[2 * k + 1];
        float dsum = hpn[(size_t)a * D + lane] * hpn[(size_t)b * D + lane] +
                     hpn[(size_t)a * D + lane + 64] * hpn[(size_t)b * D + lane + 64];
#pragma unroll
        for (int off = 32; off > 0; off >>= 1) dsum += __shfl_down(dsum, off);
        if (lane == 0) {
            float p = __expf(dsum * INV_TAU);
            part += log1pf(s_out[a] / p) + log1pf(s_out[b] / p);
        }
    }
    __shared__ float red[8];
    if (lane == 0) red[wave] = part;
    __syncthreads();
    if (threadIdx.x == 0) {
        float tot = 0.0f;
#pragma unroll
        for (int w = 0; w < 8; ++w) tot += red[w];
        atomicAdd(out, tot / (2.0f * (float)K));
    }
}

// ============================================================================
// Fallback kernels (non-cooperative), used only if a coop launch fails.
// ============================================================================
__global__ void scatter_pos_f(const int* __restrict__ pp, int* __restrict__ pos,
                              float* __restrict__ out, int K) {
    int k = blockIdx.x * blockDim.x + threadIdx.x;
    if (k == 0) *out = 0.0f;
    if (k < K) pos[pp[2 * k]] = pp[2 * k + 1];
}

__global__ void prep_kernel_f(const float* __restrict__ emb, const int* __restrict__ pos,
                              const int* __restrict__ pp, unsigned short* __restrict__ hnn,
                              float* __restrict__ hpn, int N) {
    int b = blockIdx.x, d = threadIdx.x;
    __shared__ int sP;
    __shared__ float tmp[2];
    bool isHn = (b < N);
    if (isHn && d == 0) {
        int r = b, posr = pos[r];
        int jmax = -1;
        for (int j = N - 1; j >= 0; --j)
            if (j != r && j != posr) { jmax = j; break; }
        int imax = -1;
        for (int i = N - 1; i >= 0; --i)
            if (i != r && pos[i] != r) { imax = i; break; }
        long long rowm = (jmax >= 0) ? (long long)r * N + jmax : -1;
        long long colm = (imax >= 0) ? (long long)imax * N + r : -1;
        sP = (colm > rowm) ? (imax < 0 ? 0 : imax) : (jmax < 0 ? 0 : jmax);
    }
    __syncthreads();
    float h;
    int outrow;
    if (isHn) {
        int p = sP;
        h = 0.5f * (emb[b * D + d] + emb[p * D + d]);
        outrow = b;
    } else {
        int k = b - N;
        int a = pp[2 * k], bb = pp[2 * k + 1];
        h = 1.5f * emb[a * D + d] - 0.5f * emb[bb * D + d];
        outrow = a;
    }
    float ss = h * h;
#pragma unroll
    for (int off = 32; off > 0; off >>= 1) ss += __shfl_down(ss, off);
    if ((d & 63) == 0) tmp[d >> 6] = ss;
    __syncthreads();
    float inv = 1.0f / fmaxf(sqrtf(tmp[0] + tmp[1]), 1e-8f);
    if (isHn)
        hnn[outrow * D + d] = bf16_bits(h * inv);
    else
        hpn[outrow * D + d] = h * inv;
}

__global__ __launch_bounds__(512) void select_kernel_f(const unsigned short* __restrict__ sims,
                                                       const int* __restrict__ stage,
                                                       float* __restrict__ s_out, int N, int q) {
    int wave = threadIdx.x >> 6, lane = threadIdx.x & 63;
    int row = blockIdx.x * 8 + wave;
    const unsigned short* rp = sims + (size_t)row * N;
    unsigned s[64];
#pragma unroll
    for (int j = 0; j < 8; ++j) {
        u16x8 t = *(const u16x8*)&rp[j * 512 + lane * 8];
#pragma unroll
        for (int e = 0; e < 8; ++e) s[j * 8 + e] = (unsigned)(unsigned short)t[e];
    }
    unsigned T = 0;
    if (stage[0]) {
#pragma unroll
        for (int b = 15; b >= 0; --b) {
            unsigned cand = T | (1u << b);
            int cnt = 0;
#pragma unroll
            for (int i = 0; i < 64; ++i) cnt += (s[i] < cand);
#pragma unroll
            for (int off = 1; off < 64; off <<= 1) cnt += __shfl_xor(cnt, off);
            if (cnt <= q) T = cand;
        }
    }
    float sum = 0.0f;
#pragma unroll
    for (int i = 0; i < 64; ++i) {
        if (s[i] >= T) {
            unsigned raw = (s[i] & 0x8000u) ? (s[i] ^ 0x8000u) : (~s[i] & 0xFFFFu);
            sum += __expf(__uint_as_float(raw << 16) * INV_TAU);
        }
    }
#pragma unroll
    for (int off = 1; off < 64; off <<= 1) sum += __shfl_xor(sum, off);
    if (lane == 0) s_out[row] = sum;
}

__global__ __launch_bounds__(1024) void loss_kernel_f(const float* __restrict__ hpn,
                                                      const float* __restrict__ s,
                                                      const int* __restrict__ pp,
                                                      float* __restrict__ out, int K,
                                                      float scale) {
    int wave = threadIdx.x >> 6, lane = threadIdx.x & 63;
    int k = blockIdx.x * 16 + wave;
    float part = 0.0f;
    if (k < K) {
        int a = pp[2 * k], b = pp[2 * k + 1];
        float dsum = hpn[a * D + lane] * hpn[b * D + lane] +
                     hpn[a * D + lane + 64] * hpn[b * D + lane + 64];
#pragma unroll
        for (int off = 32; off > 0; off >>= 1) dsum += __shfl_down(dsum, off);
        if (lane == 0) {
            float p = __expf(dsum * INV_TAU);
            part = log1pf(s[a] / p) + log1pf(s[b] / p);
        }
    }
    __shared__ float red[16];
    if (lane == 0) red[wave] = part;
    __syncthreads();
    if (threadIdx.x == 0) {
        float tot = 0.0f;
#pragma unroll
        for (int w = 0; w < 16; ++w) tot += red[w];
        atomicAdd(out, tot * scale);
    }
}

extern "C" void kernel_launch(void* const* d_in, const int* in_sizes, int n_in,
                              void* d_out, int out_size, void* d_ws, size_t ws_size,
                              hipStream_t stream) {
    const float* emb = (const float*)d_in[0];
    const int* pp = (const int*)d_in[1];
    const int* stage = (const int*)d_in[2];
    int N = in_sizes[0] / D;  // 4096
    int K = in_sizes[1] / 2;  // 4096 pairs

    char* ws = (char*)d_ws;
    size_t offPos = 0;
    size_t offHnn = offPos + (size_t)N * 4;       // u16 N*D
    size_t offHpn = offHnn + (size_t)N * D * 2;   // fp32 N*D
    size_t offS = offHpn + (size_t)N * D * 4;     // fp32 N
    size_t offSims = offS + (size_t)N * 4;        // u16 N*N (32 MB)
    int* pos = (int*)(ws + offPos);
    unsigned short* hnn = (unsigned short*)(ws + offHnn);
    float* hpn = (float*)(ws + offHpn);
    float* s = (float*)(ws + offS);
    unsigned short* sims = (unsigned short*)(ws + offSims);
    float* out = (float*)d_out;
    int q = (int)(0.8 * (double)(N - 1));  // 3276 for N=4096
    int nT = N >> 7;

    // --- A: scatter + prep (cooperative, 2-in-1) ---
    {
        void* args[] = {(void*)&emb, (void*)&pp, (void*)&pos, (void*)&hnn,
                        (void*)&hpn, (void*)&out, (void*)&N, (void*)&K};
        hipError_t err = hipLaunchCooperativeKernel((const void*)prep_all_kernel,
                                                    dim3(256), dim3(512), args, 0, stream);
        if (err != hipSuccess) {
            scatter_pos_f<<<(K + 255) / 256, 256, 0, stream>>>(pp, pos, out, K);
            prep_kernel_f<<<N + K, D, 0, stream>>>(emb, pos, pp, hnn, hpn, N);
        }
    }

    // --- B: symmetric GEMM (upper-triangular tiles) ---
    gemm_sim_sym<<<nT * (nT + 1) / 2, 256, 0, stream>>>(hnn, pos, sims, N);

    // --- C: select + loss (cooperative, 2-in-1) ---
    {
        void* args[] = {(void*)&sims, (void*)&stage, (void*)&hpn, (void*)&pp,
                        (void*)&s, (void*)&out, (void*)&N, (void*)&K, (void*)&q};
        hipError_t err = hipLaunchCooperativeKernel((const void*)select_loss_kernel,
                                                    dim3(256), dim3(512), args, 0, stream);
        if (err != hipSuccess) {
            select_kernel_f<<<N / 8, 512, 0, stream>>>(sims, stage, s, N, q);
            loss_kernel_f<<<(K + 15) / 16, 1024, 0, stream>>>(hpn, s, pp, out, K,
                                                              1.0f / (2.0f * K));
        }
    }
}

// Round 9
// 125.452 us; speedup vs baseline: 1.5923x; 1.5923x over previous
//
#include <hip/hip_runtime.h>
#include <hip/hip_bf16.h>
#include <math.h>

#define D 128
#define INV_TAU 5.0f

typedef short bf16x8 __attribute__((ext_vector_type(8)));
typedef unsigned short u16x8 __attribute__((ext_vector_type(8)));
typedef float f32x4 __attribute__((ext_vector_type(4)));

__device__ __forceinline__ unsigned short bf16_bits(float v) {
    __hip_bfloat16 hb = __float2bfloat16(v);
    return *(unsigned short*)&hb;
}

// ---------- K1: pos[a] = b for each pair; zero the output scalar ----------
__global__ void scatter_pos(const int* __restrict__ pp, int* __restrict__ pos,
                            float* __restrict__ out, int K) {
    int k = blockIdx.x * blockDim.x + threadIdx.x;
    if (k == 0) *out = 0.0f;
    if (k < K) pos[pp[2 * k]] = pp[2 * k + 1];
}

// ---------- K2: prep — blocks [0,N): partner (inline) + hard_neg norm -> bf16;
//                      blocks [N,N+K): hard_pos norm -> fp32 ----------
__global__ void prep_kernel(const float* __restrict__ emb, const int* __restrict__ pos,
                            const int* __restrict__ pp, unsigned short* __restrict__ hnn,
                            float* __restrict__ hpn, int N) {
    int b = blockIdx.x, d = threadIdx.x;  // blockDim = 128
    __shared__ int sP;
    __shared__ float tmp[2];
    bool isHn = (b < N);
    if (isHn && d == 0) {
        int r = b, posr = pos[r];
        int jmax = -1;
        for (int j = N - 1; j >= 0; --j)
            if (j != r && j != posr) { jmax = j; break; }
        int imax = -1;
        for (int i = N - 1; i >= 0; --i)
            if (i != r && pos[i] != r) { imax = i; break; }
        long long rowm = (jmax >= 0) ? (long long)r * N + jmax : -1;
        long long colm = (imax >= 0) ? (long long)imax * N + r : -1;
        sP = (colm > rowm) ? (imax < 0 ? 0 : imax) : (jmax < 0 ? 0 : jmax);
    }
    __syncthreads();
    float h;
    int outrow;
    if (isHn) {
        int p = sP;
        h = 0.5f * (emb[b * D + d] + emb[p * D + d]);
        outrow = b;
    } else {
        int k = b - N;
        int a = pp[2 * k], bb = pp[2 * k + 1];
        h = 1.5f * emb[a * D + d] - 0.5f * emb[bb * D + d];
        outrow = a;
    }
    float ss = h * h;
#pragma unroll
    for (int off = 32; off > 0; off >>= 1) ss += __shfl_down(ss, off);
    if ((d & 63) == 0) tmp[d >> 6] = ss;
    __syncthreads();
    float inv = 1.0f / fmaxf(sqrtf(tmp[0] + tmp[1]), 1e-8f);
    if (isHn)
        hnn[outrow * D + d] = bf16_bits(h * inv);
    else
        hpn[outrow * D + d] = h * inv;
}

// ---------- K3: symmetric 128x128-tile bf16 MFMA GEMM -> sortable-u16 sims ----------
// Only upper-triangular tiles (trow <= tcol); off-diag tiles write both the
// tile and its transpose (independent masking). 528 blocks for N=4096.
// LDS row stride 136 u16: frag ds_read_b128 <=2-way conflicts (free, m136).
__global__ __launch_bounds__(256) void gemm_sim_sym(const unsigned short* __restrict__ hnn,
                                                    const int* __restrict__ pos,
                                                    unsigned short* __restrict__ sims, int N) {
    __shared__ unsigned short As[128 * 136];
    __shared__ unsigned short Bs[128 * 136];
    __shared__ int pos_r[128], pos_c[128];
    int tid = threadIdx.x;
    int nT = N >> 7;
    int t = blockIdx.x, trow = 0;
    while (t >= nT - trow) { t -= nT - trow; ++trow; }
    int tcol = trow + t;
    int rowBase = trow * 128, colBase = tcol * 128;
    bool diag = (trow == tcol);
    if (tid < 128) pos_r[tid] = pos[rowBase + tid];
    else pos_c[tid - 128] = pos[colBase + tid - 128];

    u16x8 ra[8], rb[8];
#pragma unroll
    for (int i = 0; i < 8; ++i) {
        int idx = i * 256 + tid;
        int row = idx >> 4, seg = idx & 15;
        ra[i] = *(const u16x8*)&hnn[(size_t)(rowBase + row) * D + seg * 8];
        rb[i] = *(const u16x8*)&hnn[(size_t)(colBase + row) * D + seg * 8];
    }
#pragma unroll
    for (int i = 0; i < 8; ++i) {
        int idx = i * 256 + tid;
        int row = idx >> 4, seg = idx & 15;
        *(u16x8*)&As[row * 136 + seg * 8] = ra[i];
        *(u16x8*)&Bs[row * 136 + seg * 8] = rb[i];
    }
    __syncthreads();

    int wave = tid >> 6, lane = tid & 63;
    int quad = lane >> 4, l15 = lane & 15;
    int rowhalf = wave >> 1, colhalf = wave & 1;

    f32x4 acc[4][4] = {};
#pragma unroll
    for (int kk = 0; kk < 4; ++kk) {
        bf16x8 af[4], bf[4];
#pragma unroll
        for (int rt = 0; rt < 4; ++rt)
            af[rt] = *(const bf16x8*)&As[(rowhalf * 64 + rt * 16 + l15) * 136 + kk * 32 + quad * 8];
#pragma unroll
        for (int ct = 0; ct < 4; ++ct)
            bf[ct] = *(const bf16x8*)&Bs[(colhalf * 64 + ct * 16 + l15) * 136 + kk * 32 + quad * 8];
#pragma unroll
        for (int rt = 0; rt < 4; ++rt)
#pragma unroll
            for (int ct = 0; ct < 4; ++ct)
                acc[rt][ct] = __builtin_amdgcn_mfma_f32_16x16x32_bf16(af[rt], bf[ct],
                                                                     acc[rt][ct], 0, 0, 0);
    }
    __syncthreads();  // reuse As = C-tile, Bs = C^T-tile

#pragma unroll
    for (int rt = 0; rt < 4; ++rt) {
#pragma unroll
        for (int rg = 0; rg < 4; ++rg) {
            int rloc = rowhalf * 64 + rt * 16 + quad * 4 + rg;
            int r = rowBase + rloc;
            int pr = pos_r[rloc];
#pragma unroll
            for (int ct = 0; ct < 4; ++ct) {
                int cloc = colhalf * 64 + ct * 16 + l15;
                int c = colBase + cloc;
                unsigned short u = bf16_bits(acc[rt][ct][rg]);
                unsigned short sv = (u & 0x8000u) ? (unsigned short)~u
                                                  : (unsigned short)(u | 0x8000u);
                unsigned short svC = (c == r || c == pr) ? (unsigned short)0x0080 : sv;
                As[rloc * 136 + cloc] = svC;
                if (!diag) {
                    // transposed entry (c, r): masked iff r == pos[c] (r != c off-diag)
                    unsigned short svT = (r == pos_c[cloc]) ? (unsigned short)0x0080 : sv;
                    Bs[cloc * 136 + rloc] = svT;
                }
            }
        }
    }
    __syncthreads();

#pragma unroll
    for (int i = 0; i < 8; ++i) {
        int idx = i * 256 + tid;
        int row = idx >> 4, seg = idx & 15;
        *(u16x8*)&sims[(size_t)(rowBase + row) * N + colBase + seg * 8] =
            *(const u16x8*)&As[row * 136 + seg * 8];
    }
    if (!diag) {
#pragma unroll
        for (int i = 0; i < 8; ++i) {
            int idx = i * 256 + tid;
            int row = idx >> 4, seg = idx & 15;
            *(u16x8*)&sims[(size_t)(colBase + row) * N + rowBase + seg * 8] =
                *(const u16x8*)&Bs[row * 136 + seg * 8];
        }
    }
}

// ---------- K4: wave-per-row exact rank-select + exp-sum (register-resident) ----------
// 512 thr = 8 waves = 8 rows per block, FIXED mapping (no grid-stride: keeps the
// allocator from capping VGPRs below the 64-reg row array — R8 lesson).
__global__ __launch_bounds__(512) void select_kernel(const unsigned short* __restrict__ sims,
                                                     const int* __restrict__ stage,
                                                     float* __restrict__ s_out, int N, int q) {
    int wave = threadIdx.x >> 6, lane = threadIdx.x & 63;
    int row = blockIdx.x * 8 + wave;
    const unsigned short* rp = sims + (size_t)row * N;

    unsigned s[64];
#pragma unroll
    for (int j = 0; j < 8; ++j) {
        u16x8 t = *(const u16x8*)&rp[j * 512 + lane * 8];
#pragma unroll
        for (int e = 0; e < 8; ++e) s[j * 8 + e] = (unsigned)(unsigned short)t[e];
    }

    unsigned T = 0;
    if (stage[0]) {
#pragma unroll
        for (int b = 15; b >= 0; --b) {
            unsigned cand = T | (1u << b);
            int cnt = 0;
#pragma unroll
            for (int i = 0; i < 64; ++i) cnt += (s[i] < cand);
#pragma unroll
            for (int off = 1; off < 64; off <<= 1) cnt += __shfl_xor(cnt, off);
            if (cnt <= q) T = cand;  // rank-q element is >= cand
        }
    }

    float sum = 0.0f;
#pragma unroll
    for (int i = 0; i < 64; ++i) {
        if (s[i] >= T) {
            unsigned raw = (s[i] & 0x8000u) ? (s[i] ^ 0x8000u) : (~s[i] & 0xFFFFu);
            sum += __expf(__uint_as_float(raw << 16) * INV_TAU);
        }
    }
#pragma unroll
    for (int off = 1; off < 64; off <<= 1) sum += __shfl_xor(sum, off);
    if (lane == 0) s_out[row] = sum;
}

// ---------- K5: per-pair positive cos + two-level loss reduction ----------
__global__ __launch_bounds__(1024) void loss_kernel(const float* __restrict__ hpn,
                                                    const float* __restrict__ s,
                                                    const int* __restrict__ pp,
                                                    float* __restrict__ out, int K,
                                                    float scale) {
    int wave = threadIdx.x >> 6, lane = threadIdx.x & 63;
    int k = blockIdx.x * 16 + wave;
    float part = 0.0f;
    if (k < K) {
        int a = pp[2 * k], b = pp[2 * k + 1];
        float dsum = hpn[a * D + lane] * hpn[b * D + lane] +
                     hpn[a * D + lane + 64] * hpn[b * D + lane + 64];
#pragma unroll
        for (int off = 32; off > 0; off >>= 1) dsum += __shfl_down(dsum, off);
        if (lane == 0) {
            float p = __expf(dsum * INV_TAU);
            part = log1pf(s[a] / p) + log1pf(s[b] / p);
        }
    }
    __shared__ float red[16];
    if (lane == 0) red[wave] = part;
    __syncthreads();
    if (threadIdx.x == 0) {
        float tot = 0.0f;
#pragma unroll
        for (int w = 0; w < 16; ++w) tot += red[w];
        atomicAdd(out, tot * scale);
    }
}

extern "C" void kernel_launch(void* const* d_in, const int* in_sizes, int n_in,
                              void* d_out, int out_size, void* d_ws, size_t ws_size,
                              hipStream_t stream) {
    const float* emb = (const float*)d_in[0];
    const int* pp = (const int*)d_in[1];
    const int* stage = (const int*)d_in[2];
    int N = in_sizes[0] / D;  // 4096
    int K = in_sizes[1] / 2;  // 4096 pairs

    char* ws = (char*)d_ws;
    size_t offPos = 0;
    size_t offHnn = offPos + (size_t)N * 4;       // u16 N*D
    size_t offHpn = offHnn + (size_t)N * D * 2;   // fp32 N*D
    size_t offS = offHpn + (size_t)N * D * 4;     // fp32 N
    size_t offSims = offS + (size_t)N * 4;        // u16 N*N (32 MB)
    int* pos = (int*)(ws + offPos);
    unsigned short* hnn = (unsigned short*)(ws + offHnn);
    float* hpn = (float*)(ws + offHpn);
    float* s = (float*)(ws + offS);
    unsigned short* sims = (unsigned short*)(ws + offSims);
    int nT = N >> 7;

    scatter_pos<<<(K + 255) / 256, 256, 0, stream>>>(pp, pos, (float*)d_out, K);
    prep_kernel<<<N + K, D, 0, stream>>>(emb, pos, pp, hnn, hpn, N);
    gemm_sim_sym<<<nT * (nT + 1) / 2, 256, 0, stream>>>(hnn, pos, sims, N);
    int q = (int)(0.8 * (double)(N - 1));  // 3276 for N=4096
    select_kernel<<<N / 8, 512, 0, stream>>>(sims, stage, s, N, q);
    loss_kernel<<<(K + 15) / 16, 1024, 0, stream>>>(hpn, s, pp, (float*)d_out, K,
                                                    1.0f / (2.0f * K));
}

// Round 10
// 118.722 us; speedup vs baseline: 1.6825x; 1.0567x over previous
//
#include <hip/hip_runtime.h>
#include <hip/hip_bf16.h>
#include <math.h>

#define D 128
#define INV_TAU 5.0f

typedef short bf16x8 __attribute__((ext_vector_type(8)));
typedef unsigned short u16x8 __attribute__((ext_vector_type(8)));
typedef float f32x4 __attribute__((ext_vector_type(4)));

__device__ __forceinline__ unsigned short bf16_bits(float v) {
    __hip_bfloat16 hb = __float2bfloat16(v);
    return *(unsigned short*)&hb;
}

// ---------- K1: pos[a] = b for each pair; zero the output scalar ----------
__global__ void scatter_pos(const int* __restrict__ pp, int* __restrict__ pos,
                            float* __restrict__ out, int K) {
    int k = blockIdx.x * blockDim.x + threadIdx.x;
    if (k == 0) *out = 0.0f;
    if (k < K) pos[pp[2 * k]] = pp[2 * k + 1];
}

// ---------- K2: prep — blocks [0,N): partner (inline) + hard_neg norm -> bf16;
//                      blocks [N,N+K): hard_pos norm -> fp32 ----------
__global__ void prep_kernel(const float* __restrict__ emb, const int* __restrict__ pos,
                            const int* __restrict__ pp, unsigned short* __restrict__ hnn,
                            float* __restrict__ hpn, int N) {
    int b = blockIdx.x, d = threadIdx.x;  // blockDim = 128
    __shared__ int sP;
    __shared__ float tmp[2];
    bool isHn = (b < N);
    if (isHn && d == 0) {
        int r = b, posr = pos[r];
        int jmax = -1;
        for (int j = N - 1; j >= 0; --j)
            if (j != r && j != posr) { jmax = j; break; }
        int imax = -1;
        for (int i = N - 1; i >= 0; --i)
            if (i != r && pos[i] != r) { imax = i; break; }
        long long rowm = (jmax >= 0) ? (long long)r * N + jmax : -1;
        long long colm = (imax >= 0) ? (long long)imax * N + r : -1;
        sP = (colm > rowm) ? (imax < 0 ? 0 : imax) : (jmax < 0 ? 0 : jmax);
    }
    __syncthreads();
    float h;
    int outrow;
    if (isHn) {
        int p = sP;
        h = 0.5f * (emb[b * D + d] + emb[p * D + d]);
        outrow = b;
    } else {
        int k = b - N;
        int a = pp[2 * k], bb = pp[2 * k + 1];
        h = 1.5f * emb[a * D + d] - 0.5f * emb[bb * D + d];
        outrow = a;
    }
    float ss = h * h;
#pragma unroll
    for (int off = 32; off > 0; off >>= 1) ss += __shfl_down(ss, off);
    if ((d & 63) == 0) tmp[d >> 6] = ss;
    __syncthreads();
    float inv = 1.0f / fmaxf(sqrtf(tmp[0] + tmp[1]), 1e-8f);
    if (isHn)
        hnn[outrow * D + d] = bf16_bits(h * inv);
    else
        hpn[outrow * D + d] = h * inv;
}

// ---------- K3: 128x128-tile bf16 MFMA GEMM -> sortable-u16 sims (R7 version) ----------
// 256 thr = 4 waves; wave (rowhalf, colhalf) computes a 64x64 quadrant.
// LDS row stride 136 u16: frag ds_read_b128 <=2-way conflicts (free, m136).
// Epilogue: C-tile staged in As (LDS) -> fully-coalesced dwordx4 stores.
__global__ __launch_bounds__(256) void gemm_sim(const unsigned short* __restrict__ hnn,
                                                const int* __restrict__ pos,
                                                unsigned short* __restrict__ sims, int N) {
    __shared__ unsigned short As[128 * 136];
    __shared__ unsigned short Bs[128 * 136];
    __shared__ int pos_s[128];
    int tid = threadIdx.x;
    int rowBase = blockIdx.y * 128, colBase = blockIdx.x * 128;
    if (tid < 128) pos_s[tid] = pos[rowBase + tid];

    u16x8 ra[8], rb[8];
#pragma unroll
    for (int i = 0; i < 8; ++i) {
        int idx = i * 256 + tid;
        int row = idx >> 4, seg = idx & 15;
        ra[i] = *(const u16x8*)&hnn[(size_t)(rowBase + row) * D + seg * 8];
        rb[i] = *(const u16x8*)&hnn[(size_t)(colBase + row) * D + seg * 8];
    }
#pragma unroll
    for (int i = 0; i < 8; ++i) {
        int idx = i * 256 + tid;
        int row = idx >> 4, seg = idx & 15;
        *(u16x8*)&As[row * 136 + seg * 8] = ra[i];
        *(u16x8*)&Bs[row * 136 + seg * 8] = rb[i];
    }
    __syncthreads();

    int wave = tid >> 6, lane = tid & 63;
    int quad = lane >> 4, l15 = lane & 15;
    int rowhalf = wave >> 1, colhalf = wave & 1;

    f32x4 acc[4][4] = {};
#pragma unroll
    for (int kk = 0; kk < 4; ++kk) {
        bf16x8 af[4], bf[4];
#pragma unroll
        for (int rt = 0; rt < 4; ++rt)
            af[rt] = *(const bf16x8*)&As[(rowhalf * 64 + rt * 16 + l15) * 136 + kk * 32 + quad * 8];
#pragma unroll
        for (int ct = 0; ct < 4; ++ct)
            bf[ct] = *(const bf16x8*)&Bs[(colhalf * 64 + ct * 16 + l15) * 136 + kk * 32 + quad * 8];
#pragma unroll
        for (int rt = 0; rt < 4; ++rt)
#pragma unroll
            for (int ct = 0; ct < 4; ++ct)
                acc[rt][ct] = __builtin_amdgcn_mfma_f32_16x16x32_bf16(af[rt], bf[ct],
                                                                     acc[rt][ct], 0, 0, 0);
    }
    __syncthreads();  // done reading As/Bs; reuse As as the C-tile

#pragma unroll
    for (int rt = 0; rt < 4; ++rt) {
#pragma unroll
        for (int rg = 0; rg < 4; ++rg) {
            int rloc = rowhalf * 64 + rt * 16 + quad * 4 + rg;
            int r = rowBase + rloc;
            int pr = pos_s[rloc];
#pragma unroll
            for (int ct = 0; ct < 4; ++ct) {
                int cloc = colhalf * 64 + ct * 16 + l15;
                int c = colBase + cloc;
                unsigned short u = bf16_bits(acc[rt][ct][rg]);
                unsigned short sv = (u & 0x8000u) ? (unsigned short)~u
                                                  : (unsigned short)(u | 0x8000u);
                if (c == r || c == pr) sv = 0x0080;  // sortable(-3.39e38) -> exp == 0
                As[rloc * 136 + cloc] = sv;
            }
        }
    }
    __syncthreads();

    // coalesced write-out: 8 x dwordx4 per thread (1 KB per wave-instr)
#pragma unroll
    for (int i = 0; i < 8; ++i) {
        int idx = i * 256 + tid;
        int row = idx >> 4, seg = idx & 15;
        *(u16x8*)&sims[(size_t)(rowBase + row) * N + colBase + seg * 8] =
            *(const u16x8*)&As[row * 136 + seg * 8];
    }
}

// ---------- K4: wave-per-row exact rank-select + exp-sum (register-resident) ----------
// 512 thr = 8 waves = 8 rows, FIXED mapping (no grid-stride — R8 spill lesson).
// Counting via __ballot + popcount: compare on VALU (1 inst/value), accumulate on
// the scalar pipe; no shfl-reduction chain per step.
__global__ __launch_bounds__(512) void select_kernel(const unsigned short* __restrict__ sims,
                                                     const int* __restrict__ stage,
                                                     float* __restrict__ s_out, int N, int q) {
    int wave = threadIdx.x >> 6, lane = threadIdx.x & 63;
    int row = blockIdx.x * 8 + wave;
    const unsigned short* rp = sims + (size_t)row * N;

    unsigned s[64];
#pragma unroll
    for (int j = 0; j < 8; ++j) {
        u16x8 t = *(const u16x8*)&rp[j * 512 + lane * 8];
#pragma unroll
        for (int e = 0; e < 8; ++e) s[j * 8 + e] = (unsigned)(unsigned short)t[e];
    }

    unsigned T = 0;
    if (stage[0]) {
#pragma unroll
        for (int b = 15; b >= 0; --b) {
            unsigned cand = T | (1u << b);
            int cnt = 0;
#pragma unroll
            for (int i = 0; i < 64; ++i)
                cnt += (int)__popcll(__ballot(s[i] < cand));
            // cnt is already wave-uniform (ballot spans all 64 lanes)
            if (cnt <= q) T = cand;  // rank-q element is >= cand
        }
    }

    float sum = 0.0f;
#pragma unroll
    for (int i = 0; i < 64; ++i) {
        if (s[i] >= T) {
            unsigned raw = (s[i] & 0x8000u) ? (s[i] ^ 0x8000u) : (~s[i] & 0xFFFFu);
            sum += __expf(__uint_as_float(raw << 16) * INV_TAU);
        }
    }
#pragma unroll
    for (int off = 1; off < 64; off <<= 1) sum += __shfl_xor(sum, off);
    if (lane == 0) s_out[row] = sum;
}

// ---------- K5: per-pair positive cos + two-level loss reduction ----------
__global__ __launch_bounds__(1024) void loss_kernel(const float* __restrict__ hpn,
                                                    const float* __restrict__ s,
                                                    const int* __restrict__ pp,
                                                    float* __restrict__ out, int K,
                                                    float scale) {
    int wave = threadIdx.x >> 6, lane = threadIdx.x & 63;
    int k = blockIdx.x * 16 + wave;
    float part = 0.0f;
    if (k < K) {
        int a = pp[2 * k], b = pp[2 * k + 1];
        float dsum = hpn[a * D + lane] * hpn[b * D + lane] +
                     hpn[a * D + lane + 64] * hpn[b * D + lane + 64];
#pragma unroll
        for (int off = 32; off > 0; off >>= 1) dsum += __shfl_down(dsum, off);
        if (lane == 0) {
            float p = __expf(dsum * INV_TAU);
            part = log1pf(s[a] / p) + log1pf(s[b] / p);
        }
    }
    __shared__ float red[16];
    if (lane == 0) red[wave] = part;
    __syncthreads();
    if (threadIdx.x == 0) {
        float tot = 0.0f;
#pragma unroll
        for (int w = 0; w < 16; ++w) tot += red[w];
        atomicAdd(out, tot * scale);
    }
}

extern "C" void kernel_launch(void* const* d_in, const int* in_sizes, int n_in,
                              void* d_out, int out_size, void* d_ws, size_t ws_size,
                              hipStream_t stream) {
    const float* emb = (const float*)d_in[0];
    const int* pp = (const int*)d_in[1];
    const int* stage = (const int*)d_in[2];
    int N = in_sizes[0] / D;  // 4096
    int K = in_sizes[1] / 2;  // 4096 pairs

    char* ws = (char*)d_ws;
    size_t offPos = 0;
    size_t offHnn = offPos + (size_t)N * 4;       // u16 N*D
    size_t offHpn = offHnn + (size_t)N * D * 2;   // fp32 N*D
    size_t offS = offHpn + (size_t)N * D * 4;     // fp32 N
    size_t offSims = offS + (size_t)N * 4;        // u16 N*N (32 MB)
    int* pos = (int*)(ws + offPos);
    unsigned short* hnn = (unsigned short*)(ws + offHnn);
    float* hpn = (float*)(ws + offHpn);
    float* s = (float*)(ws + offS);
    unsigned short* sims = (unsigned short*)(ws + offSims);

    scatter_pos<<<(K + 255) / 256, 256, 0, stream>>>(pp, pos, (float*)d_out, K);
    prep_kernel<<<N + K, D, 0, stream>>>(emb, pos, pp, hnn, hpn, N);
    dim3 g(N / 128, N / 128);
    gemm_sim<<<g, 256, 0, stream>>>(hnn, pos, sims, N);
    int q = (int)(0.8 * (double)(N - 1));  // 3276 for N=4096
    select_kernel<<<N / 8, 512, 0, stream>>>(sims, stage, s, N, q);
    loss_kernel<<<(K + 15) / 16, 1024, 0, stream>>>(hpn, s, pp, (float*)d_out, K,
                                                    1.0f / (2.0f * K));
}

// Round 11
// 115.256 us; speedup vs baseline: 1.7331x; 1.0301x over previous
//
#include <hip/hip_runtime.h>
#include <hip/hip_bf16.h>
#include <math.h>

#define D 128
#define INV_TAU 5.0f

typedef short bf16x8 __attribute__((ext_vector_type(8)));
typedef unsigned short u16x8 __attribute__((ext_vector_type(8)));
typedef float f32x4 __attribute__((ext_vector_type(4)));

__device__ __forceinline__ unsigned short bf16_bits(float v) {
    __hip_bfloat16 hb = __float2bfloat16(v);
    return *(unsigned short*)&hb;
}

// ---------- K1: pos[a] = b for each pair; zero the output scalar ----------
__global__ void scatter_pos(const int* __restrict__ pp, int* __restrict__ pos,
                            float* __restrict__ out, int K) {
    int k = blockIdx.x * blockDim.x + threadIdx.x;
    if (k == 0) *out = 0.0f;
    if (k < K) pos[pp[2 * k]] = pp[2 * k + 1];
}

// ---------- K2: prep — blocks [0,N): partner (inline) + hard_neg norm -> bf16;
//                      blocks [N,N+K): hard_pos norm -> fp32 ----------
__global__ void prep_kernel(const float* __restrict__ emb, const int* __restrict__ pos,
                            const int* __restrict__ pp, unsigned short* __restrict__ hnn,
                            float* __restrict__ hpn, int N) {
    int b = blockIdx.x, d = threadIdx.x;  // blockDim = 128
    __shared__ int sP;
    __shared__ float tmp[2];
    bool isHn = (b < N);
    if (isHn && d == 0) {
        int r = b, posr = pos[r];
        int jmax = -1;
        for (int j = N - 1; j >= 0; --j)
            if (j != r && j != posr) { jmax = j; break; }
        int imax = -1;
        for (int i = N - 1; i >= 0; --i)
            if (i != r && pos[i] != r) { imax = i; break; }
        long long rowm = (jmax >= 0) ? (long long)r * N + jmax : -1;
        long long colm = (imax >= 0) ? (long long)imax * N + r : -1;
        sP = (colm > rowm) ? (imax < 0 ? 0 : imax) : (jmax < 0 ? 0 : jmax);
    }
    __syncthreads();
    float h;
    int outrow;
    if (isHn) {
        int p = sP;
        h = 0.5f * (emb[b * D + d] + emb[p * D + d]);
        outrow = b;
    } else {
        int k = b - N;
        int a = pp[2 * k], bb = pp[2 * k + 1];
        h = 1.5f * emb[a * D + d] - 0.5f * emb[bb * D + d];
        outrow = a;
    }
    float ss = h * h;
#pragma unroll
    for (int off = 32; off > 0; off >>= 1) ss += __shfl_down(ss, off);
    if ((d & 63) == 0) tmp[d >> 6] = ss;
    __syncthreads();
    float inv = 1.0f / fmaxf(sqrtf(tmp[0] + tmp[1]), 1e-8f);
    if (isHn)
        hnn[outrow * D + d] = bf16_bits(h * inv);
    else
        hpn[outrow * D + d] = h * inv;
}

// ---------- K3: 128x128-tile bf16 MFMA GEMM -> sortable-u16 sims ----------
// 256 thr = 4 waves; wave (rowhalf, colhalf) computes a 64x64 quadrant.
// LDS row stride 136 u16: frag ds_read_b128 <=2-way conflicts (free, m136).
// Epilogue: C-tile staged in As (LDS) -> fully-coalesced dwordx4 stores.
__global__ __launch_bounds__(256) void gemm_sim(const unsigned short* __restrict__ hnn,
                                                const int* __restrict__ pos,
                                                unsigned short* __restrict__ sims, int N) {
    __shared__ unsigned short As[128 * 136];
    __shared__ unsigned short Bs[128 * 136];
    __shared__ int pos_s[128];
    int tid = threadIdx.x;
    int rowBase = blockIdx.y * 128, colBase = blockIdx.x * 128;
    if (tid < 128) pos_s[tid] = pos[rowBase + tid];

    u16x8 ra[8], rb[8];
#pragma unroll
    for (int i = 0; i < 8; ++i) {
        int idx = i * 256 + tid;
        int row = idx >> 4, seg = idx & 15;
        ra[i] = *(const u16x8*)&hnn[(size_t)(rowBase + row) * D + seg * 8];
        rb[i] = *(const u16x8*)&hnn[(size_t)(colBase + row) * D + seg * 8];
    }
#pragma unroll
    for (int i = 0; i < 8; ++i) {
        int idx = i * 256 + tid;
        int row = idx >> 4, seg = idx & 15;
        *(u16x8*)&As[row * 136 + seg * 8] = ra[i];
        *(u16x8*)&Bs[row * 136 + seg * 8] = rb[i];
    }
    __syncthreads();

    int wave = tid >> 6, lane = tid & 63;
    int quad = lane >> 4, l15 = lane & 15;
    int rowhalf = wave >> 1, colhalf = wave & 1;

    f32x4 acc[4][4] = {};
#pragma unroll
    for (int kk = 0; kk < 4; ++kk) {
        bf16x8 af[4], bf[4];
#pragma unroll
        for (int rt = 0; rt < 4; ++rt)
            af[rt] = *(const bf16x8*)&As[(rowhalf * 64 + rt * 16 + l15) * 136 + kk * 32 + quad * 8];
#pragma unroll
        for (int ct = 0; ct < 4; ++ct)
            bf[ct] = *(const bf16x8*)&Bs[(colhalf * 64 + ct * 16 + l15) * 136 + kk * 32 + quad * 8];
#pragma unroll
        for (int rt = 0; rt < 4; ++rt)
#pragma unroll
            for (int ct = 0; ct < 4; ++ct)
                acc[rt][ct] = __builtin_amdgcn_mfma_f32_16x16x32_bf16(af[rt], bf[ct],
                                                                     acc[rt][ct], 0, 0, 0);
    }
    __syncthreads();  // done reading As/Bs; reuse As as the C-tile

#pragma unroll
    for (int rt = 0; rt < 4; ++rt) {
#pragma unroll
        for (int rg = 0; rg < 4; ++rg) {
            int rloc = rowhalf * 64 + rt * 16 + quad * 4 + rg;
            int r = rowBase + rloc;
            int pr = pos_s[rloc];
#pragma unroll
            for (int ct = 0; ct < 4; ++ct) {
                int cloc = colhalf * 64 + ct * 16 + l15;
                int c = colBase + cloc;
                unsigned short u = bf16_bits(acc[rt][ct][rg]);
                unsigned short sv = (u & 0x8000u) ? (unsigned short)~u
                                                  : (unsigned short)(u | 0x8000u);
                if (c == r || c == pr) sv = 0x0080;  // sortable(-3.39e38) -> exp == 0
                As[rloc * 136 + cloc] = sv;
            }
        }
    }
    __syncthreads();

    // coalesced write-out: 8 x dwordx4 per thread (1 KB per wave-instr)
#pragma unroll
    for (int i = 0; i < 8; ++i) {
        int idx = i * 256 + tid;
        int row = idx >> 4, seg = idx & 15;
        *(u16x8*)&sims[(size_t)(rowBase + row) * N + colBase + seg * 8] =
            *(const u16x8*)&As[row * 136 + seg * 8];
    }
}

// ---------- K4: wave-per-row rank-select + exp-sum + PER-ROW LOSS ----------
// 512 thr = 8 waves = 8 rows, FIXED mapping (no grid-stride — R8 spill lesson).
// Counting via __ballot + scalar popcount. Loss folded in per-row:
// pairs are mirrored and cos symmetric => loss = sum_r log1p(s_r/p_r)/K with
// p_r = exp(5 * dot(hpn[r], hpn[pos[r]])).
__global__ __launch_bounds__(512) void select_loss_kernel(
    const unsigned short* __restrict__ sims, const int* __restrict__ stage,
    const float* __restrict__ hpn, const int* __restrict__ pos,
    float* __restrict__ s_out, float* __restrict__ out, int N, int K, int q) {
    int wave = threadIdx.x >> 6, lane = threadIdx.x & 63;
    int row = blockIdx.x * 8 + wave;
    const unsigned short* rp = sims + (size_t)row * N;

    unsigned s[64];
#pragma unroll
    for (int j = 0; j < 8; ++j) {
        u16x8 t = *(const u16x8*)&rp[j * 512 + lane * 8];
#pragma unroll
        for (int e = 0; e < 8; ++e) s[j * 8 + e] = (unsigned)(unsigned short)t[e];
    }

    unsigned T = 0;
    if (stage[0]) {
#pragma unroll
        for (int b = 15; b >= 0; --b) {
            unsigned cand = T | (1u << b);
            int cnt = 0;
#pragma unroll
            for (int i = 0; i < 64; ++i)
                cnt += (int)__popcll(__ballot(s[i] < cand));
            if (cnt <= q) T = cand;  // rank-q element is >= cand
        }
    }

    float sum = 0.0f;
#pragma unroll
    for (int i = 0; i < 64; ++i) {
        if (s[i] >= T) {
            unsigned raw = (s[i] & 0x8000u) ? (s[i] ^ 0x8000u) : (~s[i] & 0xFFFFu);
            sum += __expf(__uint_as_float(raw << 16) * INV_TAU);
        }
    }
#pragma unroll
    for (int off = 1; off < 64; off <<= 1) sum += __shfl_xor(sum, off);
    if (lane == 0) s_out[row] = sum;  // kept for completeness/debug

    // ---- per-row loss term: log1p(s_row / p_row) ----
    int pr = pos[row];
    float dsum = hpn[(size_t)row * D + lane] * hpn[(size_t)pr * D + lane] +
                 hpn[(size_t)row * D + lane + 64] * hpn[(size_t)pr * D + lane + 64];
#pragma unroll
    for (int off = 32; off > 0; off >>= 1) dsum += __shfl_down(dsum, off);
    __shared__ float red[8];
    if (lane == 0) {
        float p = __expf(dsum * INV_TAU);
        red[wave] = log1pf(sum / p);
    }
    __syncthreads();
    if (threadIdx.x == 0) {
        float tot = 0.0f;
#pragma unroll
        for (int w = 0; w < 8; ++w) tot += red[w];
        atomicAdd(out, tot / (float)K);
    }
}

extern "C" void kernel_launch(void* const* d_in, const int* in_sizes, int n_in,
                              void* d_out, int out_size, void* d_ws, size_t ws_size,
                              hipStream_t stream) {
    const float* emb = (const float*)d_in[0];
    const int* pp = (const int*)d_in[1];
    const int* stage = (const int*)d_in[2];
    int N = in_sizes[0] / D;  // 4096
    int K = in_sizes[1] / 2;  // 4096 pairs

    char* ws = (char*)d_ws;
    size_t offPos = 0;
    size_t offHnn = offPos + (size_t)N * 4;       // u16 N*D
    size_t offHpn = offHnn + (size_t)N * D * 2;   // fp32 N*D
    size_t offS = offHpn + (size_t)N * D * 4;     // fp32 N
    size_t offSims = offS + (size_t)N * 4;        // u16 N*N (32 MB)
    int* pos = (int*)(ws + offPos);
    unsigned short* hnn = (unsigned short*)(ws + offHnn);
    float* hpn = (float*)(ws + offHpn);
    float* s = (float*)(ws + offS);
    unsigned short* sims = (unsigned short*)(ws + offSims);

    scatter_pos<<<(K + 255) / 256, 256, 0, stream>>>(pp, pos, (float*)d_out, K);
    prep_kernel<<<N + K, D, 0, stream>>>(emb, pos, pp, hnn, hpn, N);
    dim3 g(N / 128, N / 128);
    gemm_sim<<<g, 256, 0, stream>>>(hnn, pos, sims, N);
    int q = (int)(0.8 * (double)(N - 1));  // 3276 for N=4096
    select_loss_kernel<<<N / 8, 512, 0, stream>>>(sims, stage, hpn, pos, s,
                                                  (float*)d_out, N, K, q);
}

// Round 12
// 111.866 us; speedup vs baseline: 1.7856x; 1.0303x over previous
//
#include <hip/hip_runtime.h>
#include <hip/hip_bf16.h>
#include <math.h>

#define D 128
#define INV_TAU 5.0f

typedef short bf16x8 __attribute__((ext_vector_type(8)));
typedef unsigned short u16x8 __attribute__((ext_vector_type(8)));
typedef float f32x4 __attribute__((ext_vector_type(4)));

__device__ __forceinline__ unsigned short bf16_bits(float v) {
    __hip_bfloat16 hb = __float2bfloat16(v);
    return *(unsigned short*)&hb;
}

// ---------- K1: per-pair prep. Block k owns row a = pp[2k] (rows are covered
// exactly once since pairs are mirrored). Writes pos[a], hnn[a] (hard-neg,
// partner = largest index not in {a,b} — O(1) from mirrored-pair argmax
// reduction), hpn[a] (hard-pos). No pos-array dependency => no scatter kernel.
__global__ void prep_pair_kernel(const float* __restrict__ emb, const int* __restrict__ pp,
                                 int* __restrict__ pos, unsigned short* __restrict__ hnn,
                                 float* __restrict__ hpn, float* __restrict__ out,
                                 int N, int K) {
    int k = blockIdx.x, d = threadIdx.x;  // blockDim = 128
    int a = pp[2 * k], b = pp[2 * k + 1];
    if (k == 0 && d == 0) *out = 0.0f;
    if (d == 0) pos[a] = b;
    // partner = largest index not in {a, b}
    int p = N - 1;
    if (p == a || p == b) p = N - 2;
    if (p == a || p == b) p = N - 3;

    float ea = emb[(size_t)a * D + d];
    float hn = 0.5f * (ea + emb[(size_t)p * D + d]);
    float hp = 1.5f * ea - 0.5f * emb[(size_t)b * D + d];

    float sn = hn * hn, sp = hp * hp;
#pragma unroll
    for (int off = 32; off > 0; off >>= 1) {
        sn += __shfl_down(sn, off);
        sp += __shfl_down(sp, off);
    }
    __shared__ float tn[2], tp[2];
    if ((d & 63) == 0) { tn[d >> 6] = sn; tp[d >> 6] = sp; }
    __syncthreads();
    float invn = 1.0f / fmaxf(sqrtf(tn[0] + tn[1]), 1e-8f);
    float invp = 1.0f / fmaxf(sqrtf(tp[0] + tp[1]), 1e-8f);
    hnn[(size_t)a * D + d] = bf16_bits(hn * invn);
    hpn[(size_t)a * D + d] = hp * invp;
}

// ---------- K2: 128x128-tile bf16 MFMA GEMM -> sortable-u16 sims ----------
// 256 thr = 4 waves; wave (rowhalf, colhalf) computes a 64x64 quadrant.
// LDS row stride 136 u16: frag ds_read_b128 <=2-way conflicts (free, m136).
// Epilogue: C-tile staged in As (LDS) -> fully-coalesced dwordx4 stores.
__global__ __launch_bounds__(256) void gemm_sim(const unsigned short* __restrict__ hnn,
                                                const int* __restrict__ pos,
                                                unsigned short* __restrict__ sims, int N) {
    __shared__ unsigned short As[128 * 136];
    __shared__ unsigned short Bs[128 * 136];
    __shared__ int pos_s[128];
    int tid = threadIdx.x;
    int rowBase = blockIdx.y * 128, colBase = blockIdx.x * 128;
    if (tid < 128) pos_s[tid] = pos[rowBase + tid];

    u16x8 ra[8], rb[8];
#pragma unroll
    for (int i = 0; i < 8; ++i) {
        int idx = i * 256 + tid;
        int row = idx >> 4, seg = idx & 15;
        ra[i] = *(const u16x8*)&hnn[(size_t)(rowBase + row) * D + seg * 8];
        rb[i] = *(const u16x8*)&hnn[(size_t)(colBase + row) * D + seg * 8];
    }
#pragma unroll
    for (int i = 0; i < 8; ++i) {
        int idx = i * 256 + tid;
        int row = idx >> 4, seg = idx & 15;
        *(u16x8*)&As[row * 136 + seg * 8] = ra[i];
        *(u16x8*)&Bs[row * 136 + seg * 8] = rb[i];
    }
    __syncthreads();

    int wave = tid >> 6, lane = tid & 63;
    int quad = lane >> 4, l15 = lane & 15;
    int rowhalf = wave >> 1, colhalf = wave & 1;

    f32x4 acc[4][4] = {};
#pragma unroll
    for (int kk = 0; kk < 4; ++kk) {
        bf16x8 af[4], bf[4];
#pragma unroll
        for (int rt = 0; rt < 4; ++rt)
            af[rt] = *(const bf16x8*)&As[(rowhalf * 64 + rt * 16 + l15) * 136 + kk * 32 + quad * 8];
#pragma unroll
        for (int ct = 0; ct < 4; ++ct)
            bf[ct] = *(const bf16x8*)&Bs[(colhalf * 64 + ct * 16 + l15) * 136 + kk * 32 + quad * 8];
#pragma unroll
        for (int rt = 0; rt < 4; ++rt)
#pragma unroll
            for (int ct = 0; ct < 4; ++ct)
                acc[rt][ct] = __builtin_amdgcn_mfma_f32_16x16x32_bf16(af[rt], bf[ct],
                                                                     acc[rt][ct], 0, 0, 0);
    }
    __syncthreads();  // done reading As/Bs; reuse As as the C-tile

#pragma unroll
    for (int rt = 0; rt < 4; ++rt) {
#pragma unroll
        for (int rg = 0; rg < 4; ++rg) {
            int rloc = rowhalf * 64 + rt * 16 + quad * 4 + rg;
            int r = rowBase + rloc;
            int pr = pos_s[rloc];
#pragma unroll
            for (int ct = 0; ct < 4; ++ct) {
                int cloc = colhalf * 64 + ct * 16 + l15;
                int c = colBase + cloc;
                unsigned short u = bf16_bits(acc[rt][ct][rg]);
                unsigned short sv = (u & 0x8000u) ? (unsigned short)~u
                                                  : (unsigned short)(u | 0x8000u);
                if (c == r || c == pr) sv = 0x0080;  // sortable(-3.39e38) -> exp == 0
                As[rloc * 136 + cloc] = sv;
            }
        }
    }
    __syncthreads();

    // coalesced write-out: 8 x dwordx4 per thread (1 KB per wave-instr)
#pragma unroll
    for (int i = 0; i < 8; ++i) {
        int idx = i * 256 + tid;
        int row = idx >> 4, seg = idx & 15;
        *(u16x8*)&sims[(size_t)(rowBase + row) * N + colBase + seg * 8] =
            *(const u16x8*)&As[row * 136 + seg * 8];
    }
}

// ---------- K3: wave-per-row rank-select + exp-sum + per-row loss ----------
// 512 thr = 8 waves = 8 rows, FIXED mapping (no grid-stride — R8 spill lesson).
// Counting via __ballot + scalar popcount. loss = sum_r log1p(s_r/p_r)/K.
__global__ __launch_bounds__(512) void select_loss_kernel(
    const unsigned short* __restrict__ sims, const int* __restrict__ stage,
    const float* __restrict__ hpn, const int* __restrict__ pos,
    float* __restrict__ out, int N, int K, int q) {
    int wave = threadIdx.x >> 6, lane = threadIdx.x & 63;
    int row = blockIdx.x * 8 + wave;
    const unsigned short* rp = sims + (size_t)row * N;

    unsigned s[64];
#pragma unroll
    for (int j = 0; j < 8; ++j) {
        u16x8 t = *(const u16x8*)&rp[j * 512 + lane * 8];
#pragma unroll
        for (int e = 0; e < 8; ++e) s[j * 8 + e] = (unsigned)(unsigned short)t[e];
    }

    unsigned T = 0;
    if (stage[0]) {
#pragma unroll
        for (int b = 15; b >= 0; --b) {
            unsigned cand = T | (1u << b);
            int cnt = 0;
#pragma unroll
            for (int i = 0; i < 64; ++i)
                cnt += (int)__popcll(__ballot(s[i] < cand));
            if (cnt <= q) T = cand;  // rank-q element is >= cand
        }
    }

    float sum = 0.0f;
#pragma unroll
    for (int i = 0; i < 64; ++i) {
        if (s[i] >= T) {
            unsigned raw = (s[i] & 0x8000u) ? (s[i] ^ 0x8000u) : (~s[i] & 0xFFFFu);
            sum += __expf(__uint_as_float(raw << 16) * INV_TAU);
        }
    }
#pragma unroll
    for (int off = 1; off < 64; off <<= 1) sum += __shfl_xor(sum, off);

    // per-row loss term: log1p(s_row / p_row), p_row = exp(5*dot(hpn[row],hpn[pos]))
    int pr = pos[row];
    float dsum = hpn[(size_t)row * D + lane] * hpn[(size_t)pr * D + lane] +
                 hpn[(size_t)row * D + lane + 64] * hpn[(size_t)pr * D + lane + 64];
#pragma unroll
    for (int off = 32; off > 0; off >>= 1) dsum += __shfl_down(dsum, off);
    __shared__ float red[8];
    if (lane == 0) {
        float p = __expf(dsum * INV_TAU);
        red[wave] = log1pf(sum / p);
    }
    __syncthreads();
    if (threadIdx.x == 0) {
        float tot = 0.0f;
#pragma unroll
        for (int w = 0; w < 8; ++w) tot += red[w];
        atomicAdd(out, tot / (float)K);
    }
}

extern "C" void kernel_launch(void* const* d_in, const int* in_sizes, int n_in,
                              void* d_out, int out_size, void* d_ws, size_t ws_size,
                              hipStream_t stream) {
    const float* emb = (const float*)d_in[0];
    const int* pp = (const int*)d_in[1];
    const int* stage = (const int*)d_in[2];
    int N = in_sizes[0] / D;  // 4096
    int K = in_sizes[1] / 2;  // 4096 pairs

    char* ws = (char*)d_ws;
    size_t offPos = 0;
    size_t offHnn = offPos + (size_t)N * 4;       // u16 N*D
    size_t offHpn = offHnn + (size_t)N * D * 2;   // fp32 N*D
    size_t offSims = offHpn + (size_t)N * D * 4;  // u16 N*N (32 MB)
    int* pos = (int*)(ws + offPos);
    unsigned short* hnn = (unsigned short*)(ws + offHnn);
    float* hpn = (float*)(ws + offHpn);
    unsigned short* sims = (unsigned short*)(ws + offSims);

    prep_pair_kernel<<<K, D, 0, stream>>>(emb, pp, pos, hnn, hpn, (float*)d_out, N, K);
    dim3 g(N / 128, N / 128);
    gemm_sim<<<g, 256, 0, stream>>>(hnn, pos, sims, N);
    int q = (int)(0.8 * (double)(N - 1));  // 3276 for N=4096
    select_loss_kernel<<<N / 8, 512, 0, stream>>>(sims, stage, hpn, pos,
                                                  (float*)d_out, N, K, q);
}